// Round 1
// baseline (122.968 us; speedup 1.0000x reference)
//
#include <hip/hip_runtime.h>

#define NROWS 4
#define EPS2 1e-10f

// descending compare-exchange
#define CE(a,b) { float _hi = fmaxf(a,b), _lo = fminf(a,b); a = _hi; b = _lo; }

__launch_bounds__(256, 2)
__global__ void nfpn_fp_kernel(const float* __restrict__ dptr,
                               const float* __restrict__ W1, const float* __restrict__ b1,
                               const float* __restrict__ W2, const float* __restrict__ b2,
                               const float* __restrict__ W3, const float* __restrict__ b3,
                               float* __restrict__ out, int B)
{
    // packed weights in LDS (wave-uniform broadcast reads, conflict-free)
    __shared__ float s_w23[30][12]; // [j][0:6]=W2[j,0:6] (u part), [j][6:12]=W3[0:6][j]
    __shared__ float s_wq [30][8];  // [j][0:6]=W2[j,6:12] (Qd part), [j][6]=b2[j]
    __shared__ float s_w1 [6][4];   // [m][0:3)=W1[m,:], [m][3]=b1[m]
    __shared__ float s_b3 [8];

    const int tid = threadIdx.x;
    for (int idx = tid; idx < 360; idx += 256) {
        const int j = idx / 12, kk = idx % 12;
        s_w23[j][kk] = (kk < 6) ? W2[j * 12 + kk] : W3[(kk - 6) * 30 + j];
    }
    for (int idx = tid; idx < 240; idx += 256) {
        const int j = idx / 8, kk = idx % 8;
        s_wq[j][kk] = (kk < 6) ? W2[j * 12 + 6 + kk] : ((kk == 6) ? b2[j] : 0.0f);
    }
    if (tid < 24) { const int m = tid / 4, kk = tid % 4; s_w1[m][kk] = (kk < 3) ? W1[m * 3 + kk] : b1[m]; }
    if (tid < 6) s_b3[tid] = b3[tid];
    __syncthreads();

    const long long base = ((long long)blockIdx.x * blockDim.x + tid) * NROWS;
    if (base + NROWS > B) return;   // B % (256*NROWS) == 0 for this problem

    // ---- load d rows (contiguous, 16B aligned: 3 x float4 = 12 floats) ----
    float dd[NROWS][3];
    {
        const float4* dv = (const float4*)(dptr + base * 3);
        const float4 a = dv[0], b = dv[1], c4 = dv[2];
        dd[0][0]=a.x;  dd[0][1]=a.y;  dd[0][2]=a.z;
        dd[1][0]=a.w;  dd[1][1]=b.x;  dd[1][2]=b.y;
        dd[2][0]=b.z;  dd[2][1]=b.w;  dd[2][2]=c4.x;
        dd[3][0]=c4.y; dd[3][1]=c4.z; dd[3][2]=c4.w;
    }

    // ---- Qd = W1 d + b1 ----
    float qd[NROWS][6];
    #pragma unroll
    for (int m = 0; m < 6; ++m) {
        const float w0 = s_w1[m][0], w1v = s_w1[m][1], w2v = s_w1[m][2], bb = s_w1[m][3];
        #pragma unroll
        for (int r = 0; r < NROWS; ++r)
            qd[r][m] = fmaf(w0, dd[r][0], fmaf(w1v, dd[r][1], fmaf(w2v, dd[r][2], bb)));
    }

    // ---- c[j] = b2[j] + W2[j,6:12] . Qd   (loop-invariant) ----
    float c[NROWS][30];
    #pragma unroll
    for (int j = 0; j < 30; ++j) {
        const float4 wa = *(const float4*)&s_wq[j][0];
        const float4 wb = *(const float4*)&s_wq[j][4];
        #pragma unroll
        for (int r = 0; r < NROWS; ++r) {
            float t = wb.z;                 // b2[j]
            t = fmaf(wa.x, qd[r][0], t);
            t = fmaf(wa.y, qd[r][1], t);
            t = fmaf(wa.z, qd[r][2], t);
            t = fmaf(wa.w, qd[r][3], t);
            t = fmaf(wb.x, qd[r][4], t);
            t = fmaf(wb.y, qd[r][5], t);
            c[r][j] = t;
        }
    }

    float bb3[6];
    #pragma unroll
    for (int m = 0; m < 6; ++m) bb3[m] = s_b3[m];

    float u[NROWS][6];
    #pragma unroll
    for (int r = 0; r < NROWS; ++r)
        #pragma unroll
        for (int m = 0; m < 6; ++m) u[r][m] = 0.0f;

    // ---- fixed-point loop; last executed step is the output step ----
    bool conv = false;
    int k = 0;
    #pragma unroll 1
    while (true) {
        ++k;
        // keep LDS weight reads inside the loop (block LICM hoist -> spill)
        asm volatile("" ::: "memory");

        float acc[NROWS][6];
        #pragma unroll
        for (int r = 0; r < NROWS; ++r)
            #pragma unroll
            for (int m = 0; m < 6; ++m) acc[r][m] = bb3[m];

        #pragma unroll
        for (int j = 0; j < 30; ++j) {
            const float4 wa = *(const float4*)&s_w23[j][0];  // W2u[j][0:4]
            const float4 wb = *(const float4*)&s_w23[j][4];  // W2u[j][4:6], W3[0:2][j]
            const float4 wc = *(const float4*)&s_w23[j][8];  // W3[2:6][j]
            #pragma unroll
            for (int r = 0; r < NROWS; ++r) {
                float t = c[r][j];
                t = fmaf(wa.x, u[r][0], t);
                t = fmaf(wa.y, u[r][1], t);
                t = fmaf(wa.z, u[r][2], t);
                t = fmaf(wa.w, u[r][3], t);
                t = fmaf(wb.x, u[r][4], t);
                t = fmaf(wb.y, u[r][5], t);
                const float h = fmaxf(t, 0.1f * t);   // leaky_relu(t, 0.1)
                acc[r][0] = fmaf(wb.z, h, acc[r][0]);
                acc[r][1] = fmaf(wb.w, h, acc[r][1]);
                acc[r][2] = fmaf(wc.x, h, acc[r][2]);
                acc[r][3] = fmaf(wc.y, h, acc[r][3]);
                acc[r][4] = fmaf(wc.z, h, acc[r][4]);
                acc[r][5] = fmaf(wc.w, h, acc[r][5]);
            }
        }

        bool act = false;
        #pragma unroll
        for (int r = 0; r < NROWS; ++r) {
            // projection input v = u - Fxd = -(W3 h + b3)
            const float v0 = -acc[r][0], v1 = -acc[r][1], v2 = -acc[r][2],
                        v3 = -acc[r][3], v4 = -acc[r][4], v5 = -acc[r][5];
            // sort descending (insertion network, 15 CE)
            float s0=v0, s1=v1, s2=v2, s3=v3, s4=v4, s5=v5;
            CE(s0,s1)
            CE(s1,s2) CE(s0,s1)
            CE(s2,s3) CE(s1,s2) CE(s0,s1)
            CE(s3,s4) CE(s2,s3) CE(s1,s2) CE(s0,s1)
            CE(s4,s5) CE(s3,s4) CE(s2,s3) CE(s1,s2) CE(s0,s1)
            // theta = css[rho-1]/rho ; cond_k monotone true for k<=rho
            float css = s0 - 1.0f;
            float theta = css;                                           // k=1 always true
            css += s1; theta = (2.0f*s1 - css > 0.0f) ? css * 0.5f          : theta;
            css += s2; theta = (3.0f*s2 - css > 0.0f) ? css * (1.0f/3.0f)   : theta;
            css += s3; theta = (4.0f*s3 - css > 0.0f) ? css * 0.25f         : theta;
            css += s4; theta = (5.0f*s4 - css > 0.0f) ? css * 0.2f          : theta;
            css += s5; theta = (6.0f*s5 - css > 0.0f) ? css * (1.0f/6.0f)   : theta;

            float r2 = 0.0f;
            float un;
            un = fmaxf(v0 - theta, 0.0f); { const float dm = un - u[r][0]; r2 = fmaf(dm,dm,r2); } u[r][0] = un;
            un = fmaxf(v1 - theta, 0.0f); { const float dm = un - u[r][1]; r2 = fmaf(dm,dm,r2); } u[r][1] = un;
            un = fmaxf(v2 - theta, 0.0f); { const float dm = un - u[r][2]; r2 = fmaf(dm,dm,r2); } u[r][2] = un;
            un = fmaxf(v3 - theta, 0.0f); { const float dm = un - u[r][3]; r2 = fmaf(dm,dm,r2); } u[r][3] = un;
            un = fmaxf(v4 - theta, 0.0f); { const float dm = un - u[r][4]; r2 = fmaf(dm,dm,r2); } u[r][4] = un;
            un = fmaxf(v5 - theta, 0.0f); { const float dm = un - u[r][5]; r2 = fmaf(dm,dm,r2); } u[r][5] = un;
            act = act || (r2 > EPS2);
        }

        if (conv || k > 100) break;             // this step was the final (output) step
        conv = (__ballot(act) == 0ULL);         // wave-uniform: no divergent loop exits
    }

    // ---- store 24 contiguous floats (6 x float4, 16B aligned) ----
    float4* ov = (float4*)(out + base * 6);
    ov[0] = make_float4(u[0][0], u[0][1], u[0][2], u[0][3]);
    ov[1] = make_float4(u[0][4], u[0][5], u[1][0], u[1][1]);
    ov[2] = make_float4(u[1][2], u[1][3], u[1][4], u[1][5]);
    ov[3] = make_float4(u[2][0], u[2][1], u[2][2], u[2][3]);
    ov[4] = make_float4(u[2][4], u[2][5], u[3][0], u[3][1]);
    ov[5] = make_float4(u[3][2], u[3][3], u[3][4], u[3][5]);
}

extern "C" void kernel_launch(void* const* d_in, const int* in_sizes, int n_in,
                              void* d_out, int out_size, void* d_ws, size_t ws_size,
                              hipStream_t stream) {
    const float* dptr = (const float*)d_in[0];
    const float* W1   = (const float*)d_in[1];
    const float* b1   = (const float*)d_in[2];
    const float* W2   = (const float*)d_in[3];
    const float* b2   = (const float*)d_in[4];
    const float* W3   = (const float*)d_in[5];
    const float* b3   = (const float*)d_in[6];
    float* out = (float*)d_out;

    const int B = in_sizes[0] / 3;               // 1048576
    const int rowsPerBlock = 256 * NROWS;
    const int grid = (B + rowsPerBlock - 1) / rowsPerBlock;
    nfpn_fp_kernel<<<grid, 256, 0, stream>>>(dptr, W1, b1, W2, b2, W3, b3, out, B);
}

// Round 4
// 64.948 us; speedup vs baseline: 1.8933x; 1.8933x over previous
//
#include <hip/hip_runtime.h>

typedef _Float16 half8  __attribute__((ext_vector_type(8)));
typedef __fp16   fp16x2 __attribute__((ext_vector_type(2)));
typedef unsigned u32x2  __attribute__((ext_vector_type(2)));

#define EPS2 4e-7f
// descending compare-exchange
#define CE(a,b) { float _hi = fmaxf(a,b), _lo = fminf(a,b); a = _hi; b = _lo; }

// permlane32 swap: a' = {a.lo, b.lo}, b' = {a.hi, b.hi}
static __device__ __forceinline__ void plswap(unsigned &a, unsigned &b) {
#if __has_builtin(__builtin_amdgcn_permlane32_swap)
    u32x2 r = __builtin_amdgcn_permlane32_swap(a, b, false, false);
    a = r[0]; b = r[1];
#else
    unsigned ao, bo;
    asm("v_mov_b32 %0, %2\n\t"
        "v_mov_b32 %1, %3\n\t"
        "v_permlane32_swap_b32 %0, %1"
        : "=&v"(ao), "=&v"(bo) : "v"(a), "v"(b));
    a = ao; b = bo;
#endif
}
static __device__ __forceinline__ void plswapf(float &a, float &b) {
    union { float f; unsigned u; } ua, ub;
    ua.f = a; ub.f = b;
    plswap(ua.u, ub.u);
    a = ua.f; b = ub.f;
}

static __device__ __forceinline__ unsigned pkrtz(float a, float b) {
    union { fp16x2 h; unsigned u; } x;
    x.h = __builtin_amdgcn_cvt_pkrtz(a, b);   // lo = a, hi = b
    return x.u;
}
static __device__ __forceinline__ unsigned pk_rne(float a, float b) {
    union { _Float16 h[2]; unsigned u; } x;
    x.h[0] = (_Float16)a; x.h[1] = (_Float16)b;
    return x.u;
}
static __device__ __forceinline__ half8 mk8(unsigned a, unsigned b, unsigned c, unsigned d) {
    union { unsigned u[4]; half8 h; } x;
    x.u[0] = a; x.u[1] = b; x.u[2] = c; x.u[3] = d;
    return x.h;
}

__launch_bounds__(256, 2)
__global__ void nfpn_mfma_kernel(const float* __restrict__ dptr,
                                 const float* __restrict__ W1, const float* __restrict__ b1,
                                 const float* __restrict__ W2, const float* __restrict__ b2,
                                 const float* __restrict__ W3, const float* __restrict__ b3,
                                 float* __restrict__ out, long long B)
{
    const int lane = threadIdx.x & 63;
    const int hi   = lane >> 5;          // lane half (0: lanes 0-31, 1: lanes 32-63)
    const int col  = lane & 31;          // MFMA column / M-row index
    const long long wid = ((long long)blockIdx.x * blockDim.x + threadIdx.x) >> 6;
    const long long own = wid * 64 + (long long)hi * 32 + col;   // this lane's batch row
    if (own >= B) return;                // B % 64 == 0 -> wave-uniform

    // ---------------- A-operand fragments (one-time, RNE weight conversion) ----
    // A layout assumed: m = lane&31, k = 8*(lane>>5) + e (consistent with B => robust)
    half8 aW2u, aW3a, aW3b;
    {
        unsigned p2[4], pa[4], pb[4];
        const int rW2 = (col < 30) ? col : 0;
        const int rW3 = (col < 6) ? col : 0;
        #pragma unroll
        for (int i = 0; i < 4; ++i) {
            const int e0 = 2 * i, e1 = 2 * i + 1;
            // W2u: valid only k<6 on the low lane-half
            const int k0 = 8 * hi + e0, k1 = 8 * hi + e1;
            float x = W2[rW2 * 12 + (k0 < 6 ? k0 : 0)];
            float y = W2[rW2 * 12 + (k1 < 6 ? k1 : 0)];
            if (!(col < 30 && k0 < 6)) x = 0.0f;
            if (!(col < 30 && k1 < 6)) y = 0.0f;
            p2[i] = pk_rne(x, y);
            // W3a: k_global = 8*hi+e in [0,16) -- always < 30
            float xa = W3[rW3 * 30 + k0];
            float ya = W3[rW3 * 30 + k1];
            if (col >= 6) { xa = 0.0f; ya = 0.0f; }
            pa[i] = pk_rne(xa, ya);
            // W3b: k_global = 16 + 8*hi + e, valid < 30
            const int kb0 = 16 + k0, kb1 = 16 + k1;
            float xb = W3[rW3 * 30 + (kb0 < 30 ? kb0 : 0)];
            float yb = W3[rW3 * 30 + (kb1 < 30 ? kb1 : 0)];
            if (!(col < 6 && kb0 < 30)) xb = 0.0f;
            if (!(col < 6 && kb1 < 30)) yb = 0.0f;
            pb[i] = pk_rne(xb, yb);
        }
        aW2u = mk8(p2[0], p2[1], p2[2], p2[3]);
        aW3a = mk8(pa[0], pa[1], pa[2], pa[3]);
        aW3b = mk8(pb[0], pb[1], pb[2], pb[3]);
    }

    // ---------------- Qd for own row, then broadcast per-column (via shfl) ------
    float qd0[6], qd1[6];
    {
        const float d0 = dptr[own * 3 + 0], d1 = dptr[own * 3 + 1], d2 = dptr[own * 3 + 2];
        #pragma unroll
        for (int m = 0; m < 6; ++m) {
            float q = fmaf(W1[m * 3 + 0], d0,
                      fmaf(W1[m * 3 + 1], d1,
                      fmaf(W1[m * 3 + 2], d2, b1[m])));
            qd0[m] = __shfl(q, col);        // tile0 Qd[col] on all lanes
            qd1[m] = __shfl(q, 32 + col);   // tile1 Qd[col] on all lanes
        }
    }

    // ---------------- c tiles in C-layout (loop-invariant MFMA C-operand) -------
    float c0v[16], c1v[16];
    #pragma unroll
    for (int r = 0; r < 16; ++r) {
        const int row = (r & 3) + 8 * (r >> 2) + 4 * hi;   // verified C/D row formula
        const int rc = (row < 30) ? row : 0;
        float s0 = b2[rc], s1 = s0;
        #pragma unroll
        for (int m = 0; m < 6; ++m) {
            const float w = W2[rc * 12 + 6 + m];
            s0 = fmaf(w, qd0[m], s0);
            s1 = fmaf(w, qd1[m], s1);
        }
        const bool valid = (row < 30);
        c0v[r] = valid ? s0 : 0.0f;
        c1v[r] = valid ? s1 : 0.0f;
    }

    // b3 in C-layout rows 0..3 (lo: rows 0-3; hi: rows 4,5 then don't-care)
    float bi0, bi1, bi2, bi3;
    {
        const int r0 = 0 + 4 * hi, r1 = 1 + 4 * hi, r2_ = 2 + 4 * hi, r3 = 3 + 4 * hi;
        bi0 = (r0 < 6) ? b3[r0] : 0.0f;
        bi1 = (r1 < 6) ? b3[r1] : 0.0f;
        bi2 = (r2_ < 6) ? b3[r2_] : 0.0f;
        bi3 = (r3 < 6) ? b3[r3] : 0.0f;
    }

    // ---------------- fixed-point loop -----------------------------------------
    half8 uf0 = mk8(0, 0, 0, 0), uf1 = mk8(0, 0, 0, 0);   // u = 0
    float u0 = 0, u1 = 0, u2 = 0, u3 = 0, u4 = 0, u5 = 0;

    bool conv = false;
    int k = 0;
    #pragma unroll 1
    while (true) {
        ++k;
        // MFMA1: h_pre = W2u * U + c   (both 32-col tiles)
        typedef float f32x16 __attribute__((ext_vector_type(16)));
        f32x16 h0, h1;
        #pragma unroll
        for (int i = 0; i < 16; ++i) { h0[i] = c0v[i]; h1[i] = c1v[i]; }
        h0 = __builtin_amdgcn_mfma_f32_32x32x16_f16(aW2u, uf0, h0, 0, 0, 0);
        h1 = __builtin_amdgcn_mfma_f32_32x32x16_f16(aW2u, uf1, h1, 0, 0, 0);

        // leaky-relu (fp32) + pack to f16; reg pair (2i,2i+1) = consecutive rows
        unsigned P0[8], P1[8];
        #pragma unroll
        for (int i = 0; i < 8; ++i) {
            float x = h0[2 * i], y = h0[2 * i + 1];
            x = fmaxf(x, 0.1f * x); y = fmaxf(y, 0.1f * y);
            P0[i] = pkrtz(x, y);
            float z = h1[2 * i], w = h1[2 * i + 1];
            z = fmaxf(z, 0.1f * z); w = fmaxf(w, 0.1f * w);
            P1[i] = pkrtz(z, w);
        }
        // C-layout -> B-operand layout: 4 swaps per tile
        plswap(P0[0], P0[2]); plswap(P0[1], P0[3]); plswap(P0[4], P0[6]); plswap(P0[5], P0[7]);
        plswap(P1[0], P1[2]); plswap(P1[1], P1[3]); plswap(P1[4], P1[6]); plswap(P1[5], P1[7]);

        // MFMA2: v_pre = W3 * h + b3 (K split 0..15 / 16..29); rows >=6 are junk
        f32x16 acc2_0, acc2_1;
        #pragma unroll
        for (int i = 0; i < 16; ++i) { acc2_0[i] = 0.0f; acc2_1[i] = 0.0f; }
        acc2_0[0] = bi0; acc2_0[1] = bi1; acc2_0[2] = bi2; acc2_0[3] = bi3;
        acc2_1[0] = bi0; acc2_1[1] = bi1; acc2_1[2] = bi2; acc2_1[3] = bi3;
        acc2_0 = __builtin_amdgcn_mfma_f32_32x32x16_f16(aW3a, mk8(P0[0], P0[1], P0[2], P0[3]), acc2_0, 0, 0, 0);
        acc2_0 = __builtin_amdgcn_mfma_f32_32x32x16_f16(aW3b, mk8(P0[4], P0[5], P0[6], P0[7]), acc2_0, 0, 0, 0);
        acc2_1 = __builtin_amdgcn_mfma_f32_32x32x16_f16(aW3a, mk8(P1[0], P1[1], P1[2], P1[3]), acc2_1, 0, 0, 0);
        acc2_1 = __builtin_amdgcn_mfma_f32_32x32x16_f16(aW3b, mk8(P1[4], P1[5], P1[6], P1[7]), acc2_1, 0, 0, 0);

        // gather v0..v5 of this lane's own element (lo lanes: tile0, hi: tile1)
        float x0 = acc2_0[0], y0 = acc2_1[0]; plswapf(x0, y0);   // x0 -> v0, y0 -> v4
        float x1 = acc2_0[1], y1 = acc2_1[1]; plswapf(x1, y1);   // x1 -> v1, y1 -> v5
        float x2 = acc2_0[2], y2 = acc2_1[2]; plswapf(x2, y2);   // x2 -> v2
        float x3 = acc2_0[3], y3 = acc2_1[3]; plswapf(x3, y3);   // x3 -> v3
        const float v0 = -x0, v1 = -x1, v2 = -x2, v3 = -x3, v4 = -y0, v5 = -y1;

        // simplex projection (fp32)
        float s0 = v0, s1 = v1, s2 = v2, s3 = v3, s4 = v4, s5 = v5;
        CE(s0, s1)
        CE(s1, s2) CE(s0, s1)
        CE(s2, s3) CE(s1, s2) CE(s0, s1)
        CE(s3, s4) CE(s2, s3) CE(s1, s2) CE(s0, s1)
        CE(s4, s5) CE(s3, s4) CE(s2, s3) CE(s1, s2) CE(s0, s1)
        float css = s0 - 1.0f;
        float theta = css;
        css += s1; theta = (2.0f * s1 - css > 0.0f) ? css * 0.5f          : theta;
        css += s2; theta = (3.0f * s2 - css > 0.0f) ? css * (1.0f / 3.0f) : theta;
        css += s3; theta = (4.0f * s3 - css > 0.0f) ? css * 0.25f         : theta;
        css += s4; theta = (5.0f * s4 - css > 0.0f) ? css * 0.2f          : theta;
        css += s5; theta = (6.0f * s5 - css > 0.0f) ? css * (1.0f / 6.0f) : theta;

        float r2 = 0.0f, un;
        un = fmaxf(v0 - theta, 0.0f); { const float dm = un - u0; r2 = fmaf(dm, dm, r2); } u0 = un;
        un = fmaxf(v1 - theta, 0.0f); { const float dm = un - u1; r2 = fmaf(dm, dm, r2); } u1 = un;
        un = fmaxf(v2 - theta, 0.0f); { const float dm = un - u2; r2 = fmaf(dm, dm, r2); } u2 = un;
        un = fmaxf(v3 - theta, 0.0f); { const float dm = un - u3; r2 = fmaf(dm, dm, r2); } u3 = un;
        un = fmaxf(v4 - theta, 0.0f); { const float dm = un - u4; r2 = fmaf(dm, dm, r2); } u4 = un;
        un = fmaxf(v5 - theta, 0.0f); { const float dm = un - u5; r2 = fmaf(dm, dm, r2); } u5 = un;
        const bool act = (r2 > EPS2);

        if (conv || k > 100) break;           // this step was the output step
        conv = (__ballot(act) == 0ULL);       // 64-row granularity

        // repack u -> B-operand f16 fragments for both tiles
        unsigned q0 = pkrtz(u0, u1), q1 = pkrtz(u2, u3), q2 = pkrtz(u4, u5);
        unsigned t0 = q0, t1 = q1, t2 = q2;
        plswap(q0, t0);   // q0 = {q0.lo, q0.lo} (tile0), t0 = {q0.hi, q0.hi} (tile1)
        plswap(q1, t1);
        plswap(q2, t2);
        uf0 = mk8(q0, q1, q2, 0);             // k=0..5 valid; k>=6 zero / junk x 0
        uf1 = mk8(t0, t1, t2, 0);
    }

    // ---------------- store (24 B per row, contiguous within wave) --------------
    float2* o2 = (float2*)(out + own * 6);
    o2[0] = make_float2(u0, u1);
    o2[1] = make_float2(u2, u3);
    o2[2] = make_float2(u4, u5);
}

extern "C" void kernel_launch(void* const* d_in, const int* in_sizes, int n_in,
                              void* d_out, int out_size, void* d_ws, size_t ws_size,
                              hipStream_t stream) {
    const float* dptr = (const float*)d_in[0];
    const float* W1   = (const float*)d_in[1];
    const float* b1   = (const float*)d_in[2];
    const float* W2   = (const float*)d_in[3];
    const float* b2   = (const float*)d_in[4];
    const float* W3   = (const float*)d_in[5];
    const float* b3   = (const float*)d_in[6];
    float* out = (float*)d_out;

    const long long B = in_sizes[0] / 3;            // 1048576
    const int rowsPerBlock = 256;                   // 4 waves x 64 rows
    const int grid = (int)((B + rowsPerBlock - 1) / rowsPerBlock);
    nfpn_mfma_kernel<<<grid, 256, 0, stream>>>(dptr, W1, b1, W2, b2, W3, b3, out, B);
}

// Round 5
// 51.847 us; speedup vs baseline: 2.3718x; 1.2527x over previous
//
#include <hip/hip_runtime.h>

typedef _Float16 half8  __attribute__((ext_vector_type(8)));
typedef __fp16   fp16x2 __attribute__((ext_vector_type(2)));
typedef unsigned u32x2  __attribute__((ext_vector_type(2)));
typedef float    f32x16 __attribute__((ext_vector_type(16)));

#define EPS2 1.6e-6f
// descending compare-exchange
#define CE(a,b) { float _hi = fmaxf(a,b), _lo = fminf(a,b); a = _hi; b = _lo; }

// permlane32 swap: a' = {a.lo, b.lo}, b' = {a.hi, b.hi}
static __device__ __forceinline__ void plswap(unsigned &a, unsigned &b) {
#if __has_builtin(__builtin_amdgcn_permlane32_swap)
    u32x2 r = __builtin_amdgcn_permlane32_swap(a, b, false, false);
    a = r[0]; b = r[1];
#else
    unsigned ao, bo;
    asm("v_mov_b32 %0, %2\n\t"
        "v_mov_b32 %1, %3\n\t"
        "v_permlane32_swap_b32 %0, %1"
        : "=&v"(ao), "=&v"(bo) : "v"(a), "v"(b));
    a = ao; b = bo;
#endif
}
static __device__ __forceinline__ void plswapf(float &a, float &b) {
    union { float f; unsigned u; } ua, ub;
    ua.f = a; ub.f = b;
    plswap(ua.u, ub.u);
    a = ua.f; b = ub.f;
}

static __device__ __forceinline__ unsigned pkrtz(float a, float b) {
    union { fp16x2 h; unsigned u; } x;
    x.h = __builtin_amdgcn_cvt_pkrtz(a, b);   // lo = a, hi = b
    return x.u;
}
// pack to f16 then packed leaky-relu: max(p, p*0.1) via v_pk_mul/v_pk_max
static __device__ __forceinline__ unsigned pk_leaky(float a, float b, fp16x2 slope) {
    union { fp16x2 h; unsigned u; } x;
    x.h = __builtin_amdgcn_cvt_pkrtz(a, b);
    fp16x2 m = x.h * slope;
    x.h = __builtin_elementwise_max(x.h, m);
    return x.u;
}
static __device__ __forceinline__ unsigned pk_rne(float a, float b) {
    union { _Float16 h[2]; unsigned u; } x;
    x.h[0] = (_Float16)a; x.h[1] = (_Float16)b;
    return x.u;
}
static __device__ __forceinline__ half8 mk8(unsigned a, unsigned b, unsigned c, unsigned d) {
    union { unsigned u[4]; half8 h; } x;
    x.u[0] = a; x.u[1] = b; x.u[2] = c; x.u[3] = d;
    return x.h;
}

__launch_bounds__(256, 2)
__global__ void nfpn_mfma_kernel(const float* __restrict__ dptr,
                                 const float* __restrict__ W1, const float* __restrict__ b1,
                                 const float* __restrict__ W2, const float* __restrict__ b2,
                                 const float* __restrict__ W3, const float* __restrict__ b3,
                                 float* __restrict__ out, long long B)
{
    const int lane = threadIdx.x & 63;
    const int hi   = lane >> 5;          // lane half (0: lanes 0-31, 1: lanes 32-63)
    const int col  = lane & 31;          // MFMA column / M-row index
    const long long wid = ((long long)blockIdx.x * blockDim.x + threadIdx.x) >> 6;
    const long long own = wid * 64 + (long long)hi * 32 + col;   // this lane's batch row
    if (own >= B) return;                // B % 64 == 0 -> wave-uniform

    // ---------------- A-operand fragments (one-time, RNE weight conversion) ----
    // A layout: m = lane&31, k = 8*(lane>>5) + e (consistent with B operand)
    half8 aW2u, aW3a, aW3b;
    {
        unsigned p2[4], pa[4], pb[4];
        const int rW2 = (col < 30) ? col : 0;
        const int rW3 = (col < 6) ? col : 0;
        #pragma unroll
        for (int i = 0; i < 4; ++i) {
            const int e0 = 2 * i, e1 = 2 * i + 1;
            const int k0 = 8 * hi + e0, k1 = 8 * hi + e1;
            float x = W2[rW2 * 12 + (k0 < 6 ? k0 : 0)];
            float y = W2[rW2 * 12 + (k1 < 6 ? k1 : 0)];
            if (!(col < 30 && k0 < 6)) x = 0.0f;
            if (!(col < 30 && k1 < 6)) y = 0.0f;
            p2[i] = pk_rne(x, y);
            float xa = W3[rW3 * 30 + k0];
            float ya = W3[rW3 * 30 + k1];
            if (col >= 6) { xa = 0.0f; ya = 0.0f; }
            pa[i] = pk_rne(xa, ya);
            const int kb0 = 16 + k0, kb1 = 16 + k1;
            float xb = W3[rW3 * 30 + (kb0 < 30 ? kb0 : 0)];
            float yb = W3[rW3 * 30 + (kb1 < 30 ? kb1 : 0)];
            if (!(col < 6 && kb0 < 30)) xb = 0.0f;
            if (!(col < 6 && kb1 < 30)) yb = 0.0f;
            pb[i] = pk_rne(xb, yb);
        }
        aW2u = mk8(p2[0], p2[1], p2[2], p2[3]);
        aW3a = mk8(pa[0], pa[1], pa[2], pa[3]);
        aW3b = mk8(pb[0], pb[1], pb[2], pb[3]);
    }

    // ---------------- Qd for own row, broadcast per-column (shfl) ---------------
    float qd0[6], qd1[6];
    {
        const float d0 = dptr[own * 3 + 0], d1 = dptr[own * 3 + 1], d2 = dptr[own * 3 + 2];
        #pragma unroll
        for (int m = 0; m < 6; ++m) {
            float q = fmaf(W1[m * 3 + 0], d0,
                      fmaf(W1[m * 3 + 1], d1,
                      fmaf(W1[m * 3 + 2], d2, b1[m])));
            qd0[m] = __shfl(q, col);        // tile0 Qd[col]
            qd1[m] = __shfl(q, 32 + col);   // tile1 Qd[col]
        }
    }

    // ---------------- persistent C-operands (read-only in the loop) -------------
    // c tiles in C-layout: MFMA1's C operand (loop-invariant Qd part of fc2)
    f32x16 c0vv, c1vv;
    #pragma unroll
    for (int r = 0; r < 16; ++r) {
        const int row = (r & 3) + 8 * (r >> 2) + 4 * hi;   // verified C/D row formula
        const int rc = (row < 30) ? row : 0;
        float s0 = b2[rc], s1 = s0;
        #pragma unroll
        for (int m = 0; m < 6; ++m) {
            const float w = W2[rc * 12 + 6 + m];
            s0 = fmaf(w, qd0[m], s0);
            s1 = fmaf(w, qd1[m], s1);
        }
        const bool valid = (row < 30);
        c0vv[r] = valid ? s0 : 0.0f;
        c1vv[r] = valid ? s1 : 0.0f;
    }
    // b3 in C-layout rows: MFMA2's C operand
    f32x16 cb;
    #pragma unroll
    for (int i = 0; i < 16; ++i) cb[i] = 0.0f;
    {
        const int r0 = 0 + 4 * hi, r1 = 1 + 4 * hi, r2_ = 2 + 4 * hi, r3 = 3 + 4 * hi;
        cb[0] = (r0 < 6) ? b3[r0] : 0.0f;
        cb[1] = (r1 < 6) ? b3[r1] : 0.0f;
        cb[2] = (r2_ < 6) ? b3[r2_] : 0.0f;
        cb[3] = (r3 < 6) ? b3[r3] : 0.0f;
    }

    const fp16x2 slope = { (__fp16)0.1f, (__fp16)0.1f };

    // ---------------- fixed-point loop -----------------------------------------
    half8 uf0 = mk8(0, 0, 0, 0), uf1 = mk8(0, 0, 0, 0);   // u = 0
    float u0 = 0, u1 = 0, u2 = 0, u3 = 0, u4 = 0, u5 = 0;

    bool conv = false;
    int k = 0;
    #pragma unroll 1
    while (true) {
        ++k;
        // MFMA1: h_pre = W2u * U + c   (C = persistent c-tiles, no copies)
        f32x16 h0 = __builtin_amdgcn_mfma_f32_32x32x16_f16(aW2u, uf0, c0vv, 0, 0, 0);
        f32x16 h1 = __builtin_amdgcn_mfma_f32_32x32x16_f16(aW2u, uf1, c1vv, 0, 0, 0);

        // pack to f16, packed leaky-relu; reg pair (2i,2i+1) = consecutive rows
        unsigned P0[8], P1[8];
        #pragma unroll
        for (int i = 0; i < 8; ++i) {
            P0[i] = pk_leaky(h0[2 * i], h0[2 * i + 1], slope);
            P1[i] = pk_leaky(h1[2 * i], h1[2 * i + 1], slope);
        }
        // C-layout -> B-operand layout: 4 swaps per tile
        plswap(P0[0], P0[2]); plswap(P0[1], P0[3]); plswap(P0[4], P0[6]); plswap(P0[5], P0[7]);
        plswap(P1[0], P1[2]); plswap(P1[1], P1[3]); plswap(P1[4], P1[6]); plswap(P1[5], P1[7]);

        // MFMA2: v_pre = W3 * h + b3 (C = persistent cb; K split 0..15/16..29)
        f32x16 acc2_0 = __builtin_amdgcn_mfma_f32_32x32x16_f16(aW3a, mk8(P0[0], P0[1], P0[2], P0[3]), cb, 0, 0, 0);
        acc2_0 = __builtin_amdgcn_mfma_f32_32x32x16_f16(aW3b, mk8(P0[4], P0[5], P0[6], P0[7]), acc2_0, 0, 0, 0);
        f32x16 acc2_1 = __builtin_amdgcn_mfma_f32_32x32x16_f16(aW3a, mk8(P1[0], P1[1], P1[2], P1[3]), cb, 0, 0, 0);
        acc2_1 = __builtin_amdgcn_mfma_f32_32x32x16_f16(aW3b, mk8(P1[4], P1[5], P1[6], P1[7]), acc2_1, 0, 0, 0);

        // gather v0..v5 of this lane's own element (lo lanes: tile0, hi: tile1)
        float x0 = acc2_0[0], y0 = acc2_1[0]; plswapf(x0, y0);   // x0 -> v0, y0 -> v4
        float x1 = acc2_0[1], y1 = acc2_1[1]; plswapf(x1, y1);   // x1 -> v1, y1 -> v5
        float x2 = acc2_0[2], y2 = acc2_1[2]; plswapf(x2, y2);   // x2 -> v2
        float x3 = acc2_0[3], y3 = acc2_1[3]; plswapf(x3, y3);   // x3 -> v3
        const float v0 = -x0, v1 = -x1, v2 = -x2, v3 = -x3, v4 = -y0, v5 = -y1;

        // simplex projection (fp32); optimal 12-comparator sort network (desc)
        float s0 = v0, s1 = v1, s2 = v2, s3 = v3, s4 = v4, s5 = v5;
        CE(s0, s5) CE(s1, s3) CE(s2, s4)
        CE(s1, s2) CE(s3, s4)
        CE(s0, s3) CE(s2, s5)
        CE(s0, s1) CE(s2, s3) CE(s4, s5)
        CE(s1, s2) CE(s3, s4)
        float css = s0 - 1.0f;
        float theta = css;
        css += s1; theta = (2.0f * s1 - css > 0.0f) ? css * 0.5f          : theta;
        css += s2; theta = (3.0f * s2 - css > 0.0f) ? css * (1.0f / 3.0f) : theta;
        css += s3; theta = (4.0f * s3 - css > 0.0f) ? css * 0.25f         : theta;
        css += s4; theta = (5.0f * s4 - css > 0.0f) ? css * 0.2f          : theta;
        css += s5; theta = (6.0f * s5 - css > 0.0f) ? css * (1.0f / 6.0f) : theta;

        float r2 = 0.0f, un;
        un = fmaxf(v0 - theta, 0.0f); { const float dm = un - u0; r2 = fmaf(dm, dm, r2); } u0 = un;
        un = fmaxf(v1 - theta, 0.0f); { const float dm = un - u1; r2 = fmaf(dm, dm, r2); } u1 = un;
        un = fmaxf(v2 - theta, 0.0f); { const float dm = un - u2; r2 = fmaf(dm, dm, r2); } u2 = un;
        un = fmaxf(v3 - theta, 0.0f); { const float dm = un - u3; r2 = fmaf(dm, dm, r2); } u3 = un;
        un = fmaxf(v4 - theta, 0.0f); { const float dm = un - u4; r2 = fmaf(dm, dm, r2); } u4 = un;
        un = fmaxf(v5 - theta, 0.0f); { const float dm = un - u5; r2 = fmaf(dm, dm, r2); } u5 = un;
        const bool act = (r2 > EPS2);

        if (conv || k > 100) break;           // this step was the output step
        conv = (__ballot(act) == 0ULL);       // 64-row granularity

        // repack u -> B-operand f16 fragments for both tiles
        unsigned q0 = pkrtz(u0, u1), q1 = pkrtz(u2, u3), q2 = pkrtz(u4, u5);
        unsigned t0 = q0, t1 = q1, t2 = q2;
        plswap(q0, t0);
        plswap(q1, t1);
        plswap(q2, t2);
        uf0 = mk8(q0, q1, q2, 0);             // k=0..5 valid; k>=6 zero
        uf1 = mk8(t0, t1, t2, 0);
    }

    // ---------------- store (24 B per row, contiguous within wave) --------------
    float2* o2 = (float2*)(out + own * 6);
    o2[0] = make_float2(u0, u1);
    o2[1] = make_float2(u2, u3);
    o2[2] = make_float2(u4, u5);
}

extern "C" void kernel_launch(void* const* d_in, const int* in_sizes, int n_in,
                              void* d_out, int out_size, void* d_ws, size_t ws_size,
                              hipStream_t stream) {
    const float* dptr = (const float*)d_in[0];
    const float* W1   = (const float*)d_in[1];
    const float* b1   = (const float*)d_in[2];
    const float* W2   = (const float*)d_in[3];
    const float* b2   = (const float*)d_in[4];
    const float* W3   = (const float*)d_in[5];
    const float* b3   = (const float*)d_in[6];
    float* out = (float*)d_out;

    const long long B = in_sizes[0] / 3;            // 1048576
    const int rowsPerBlock = 256;                   // 4 waves x 64 rows
    const int grid = (int)((B + rowsPerBlock - 1) / rowsPerBlock);
    nfpn_mfma_kernel<<<grid, 256, 0, stream>>>(dptr, W1, b1, W2, b2, W3, b3, out, B);
}